// Round 15
// baseline (258.968 us; speedup 1.0000x reference)
//
#include <hip/hip_runtime.h>
#include <hip/hip_bf16.h>

typedef __bf16 bf16_t;
typedef __bf16 bf16x8 __attribute__((ext_vector_type(8)));
typedef float f32x4 __attribute__((ext_vector_type(4)));
typedef int i32x4 __attribute__((ext_vector_type(4)));

#define S_TOT 12288
#define F_IN 128
#define F_OUT 256
#define EPS 1e-5f

static __device__ __forceinline__ float silu_f(float v) {
  return v / (1.0f + __expf(-v));
}

static __device__ __forceinline__ void gll16(const bf16_t* g, bf16_t* l) {
  __builtin_amdgcn_global_load_lds(
      (const __attribute__((address_space(1))) void*)(const void*)g,
      (__attribute__((address_space(3))) void*)(void*)l, 16, 0, 0);
}

// Device-scope spin barrier. SAFE ONLY when all n blocks are co-resident
// (grids here are sized to exact CU capacity; see residency notes per kernel).
static __device__ __forceinline__ void grid_barrier(int* cnt, int n) {
  __syncthreads();
  if (threadIdx.x == 0) {
    __threadfence();   // release: make this block's stores/atomics visible
    __hip_atomic_fetch_add(cnt, 1, __ATOMIC_ACQ_REL, __HIP_MEMORY_SCOPE_AGENT);
    while (__hip_atomic_load(cnt, __ATOMIC_ACQUIRE, __HIP_MEMORY_SCOPE_AGENT) < n)
      __builtin_amdgcn_s_sleep(2);
    __threadfence();   // acquire: invalidate stale cached copies
  }
  __syncthreads();
}

// ---------------- fusedA: weight pack (blocks 0..447) + GN1 stats+apply ------
// Sync blocks 448..1215 (768 = exactly 3/CU x 256 CUs at 33.3KB LDS,
// launch_bounds(256,3)). Pack blocks terminate -> backfill guarantees all 768
// sync blocks co-resident -> spin barrier is deadlock-free.
// Each sync block: stage 32KB x-slice in LDS + partial stats -> barrier ->
// coeffs -> apply from LDS -> h1. x is read ONCE.
__global__ __launch_bounds__(256, 3) void fusedA(
    const float* __restrict__ W1, const float* __restrict__ W2,
    const float* __restrict__ Wsk, bf16_t* __restrict__ W1p,
    bf16_t* __restrict__ W2p, bf16_t* __restrict__ Wsp,
    const float* __restrict__ x, float* __restrict__ sum1,
    float* __restrict__ ss1, const float* __restrict__ gs,
    const float* __restrict__ gb, bf16_t* __restrict__ h1,
    int* __restrict__ cnt) {
  __shared__ float sl[8192];
  __shared__ float gsq[64];
  __shared__ float aco[128], bco[128];
  int t = threadIdx.x;
  if (blockIdx.x < 448) {
    // ---- pack weights, CHUNK-MAJOR (kcg = chunk*9 + tap) ----
    int w = blockIdx.x * 4 + (t >> 6);
    int l = t & 63;
    int lo = l & 15, hi = l >> 4;
    const float* src;
    bf16_t* dst;
    int fbase, obase;
    if (w < 576) {
      int kcg = w >> 4, cb = w & 15;
      int tap = kcg % 9, chunk = kcg / 9;
      src = W1 + tap * 32768;
      dst = W1p + (size_t)w * 512;
      fbase = 32 * chunk + 8 * hi; obase = 16 * cb + lo;
    } else if (w < 1728) {
      int idx = w - 576;
      int kcg = idx >> 4, cb = idx & 15;
      int tap = kcg % 9, chunk = kcg / 9;
      src = W2 + tap * 65536;
      dst = W2p + (size_t)idx * 512;
      fbase = 32 * chunk + 8 * hi; obase = 16 * cb + lo;
    } else {
      int idx = w - 1728;
      int kc = idx >> 4, cb = idx & 15;
      src = Wsk;
      dst = Wsp + (size_t)idx * 512;
      fbase = 32 * kc + 8 * hi; obase = 16 * cb + lo;
    }
    bf16x8 v;
#pragma unroll
    for (int j = 0; j < 8; ++j)
      v[j] = (bf16_t)src[(fbase + j) * 256 + obase];
    *(bf16x8*)(dst + l * 8) = v;
    return;
  }
  // ---- sync block: slice = 64 rows x 128 ch of one vt ----
  int b = blockIdx.x - 448;            // 0..767
  int vt = b / 192;
  size_t base = (size_t)b * 8192;      // == (vt*S_TOT + (b%192)*64) * 128
  float s_ = 0.f, q_ = 0.f;
#pragma unroll
  for (int i = 0; i < 8; ++i) {
    int idx = i * 1024 + t * 4;
    f32x4 v = *(const f32x4*)(x + base + idx);
    *(f32x4*)&sl[idx] = v;
    s_ += v[0] + v[1] + v[2] + v[3];
    q_ += v[0]*v[0] + v[1]*v[1] + v[2]*v[2] + v[3]*v[3];
  }
  if (t < 64) gsq[t] = 0.f;
  __syncthreads();
  atomicAdd(&gsq[t & 31], s_);
  atomicAdd(&gsq[32 + (t & 31)], q_);
  __syncthreads();
  if (t < 32) {
    atomicAdd(&sum1[vt * 32 + t], gsq[t]);
    atomicAdd(&ss1[vt * 32 + t], gsq[32 + t]);
  }
  grid_barrier(cnt, 768);
  if (t < 32) {
    float N = (float)(S_TOT * 4);
    float mean = sum1[vt * 32 + t] / N;
    float var = ss1[vt * 32 + t] / N - mean * mean;
    float r = rsqrtf(var + EPS);
#pragma unroll
    for (int j = 0; j < 4; ++j) {
      int c = t * 4 + j;
      float a = r * gs[c];
      aco[c] = a;
      bco[c] = gb[c] - mean * a;
    }
  }
  __syncthreads();
  int c0 = (t * 8) & 127;
  f32x4 A0 = *(const f32x4*)&aco[c0];
  f32x4 A1 = *(const f32x4*)&aco[c0 + 4];
  f32x4 B0 = *(const f32x4*)&bco[c0];
  f32x4 B1 = *(const f32x4*)&bco[c0 + 4];
#pragma unroll
  for (int i = 0; i < 4; ++i) {
    int idx = i * 2048 + t * 8;
    f32x4 v0 = *(const f32x4*)&sl[idx];
    f32x4 v1 = *(const f32x4*)&sl[idx + 4];
    bf16x8 o;
#pragma unroll
    for (int j = 0; j < 4; ++j) o[j] = (bf16_t)silu_f(v0[j] * A0[j] + B0[j]);
#pragma unroll
    for (int j = 0; j < 4; ++j) o[4 + j] = (bf16_t)silu_f(v1[j] * A1[j] + B1[j]);
    *(bf16x8*)(h1 + base + idx) = o;
  }
}

// ---------------- unified gather-conv GEMM (v13 core, unchanged schedule) ----
// Block 96 rows x 256 cols, 4 waves of 96x64, acc[6][4]. Grid 512 = 2 blocks/CU
// (196 regs -> exactly 2 waves/SIMD; all 512 co-resident). K64 per barrier;
// ring-3 A via gll; B 8 asm dwordx4 reg-dbuf; steady vmcnt(11).
// !XSK (conv1): epilogue = GN2 stats from acc -> grid_barrier -> coeffs in dead
// LDS -> apply affine+SiLU to register acc -> single bf16 store (h2).
// XSK (conv2): unchanged f32 out + skip tail.
template<int RE, int NM64, bool XSK>
__global__ __launch_bounds__(256, 2) void conv_kernel(
    const bf16_t* __restrict__ hsrc, const bf16_t* __restrict__ Wp,
    const bf16_t* __restrict__ Wsp, const float* __restrict__ x,
    const int* __restrict__ adjc, const float* __restrict__ bias,
    const float* __restrict__ biask, bf16_t* __restrict__ outb,
    float* __restrict__ outf, float* __restrict__ sum_c, float* __restrict__ ss_c,
    const float* __restrict__ g2s, const float* __restrict__ g2b,
    int* __restrict__ cnt) {
  const int tid = threadIdx.x;
  const int wv = tid >> 6, l = tid & 63;
  const int lo = l & 15, hi = l >> 4;
  const int nw = wv;

  int swz = ((blockIdx.x & 7) << 6) + (blockIdx.x >> 3);   // bijective: 512 = 8*64
  int vt = swz >> 7;
  int rem = swz & 127;
  int s0 = rem * 96;

  __shared__ int adjs[864];
  __shared__ bf16_t ab[3][2][3072];   // ring-3, 2 chunks, 96 rows x 32 (64B rows)

  for (int i = tid; i < 864; i += 256) adjs[i] = adjc[s0 * 9 + i];
  __syncthreads();

  const bf16_t* hb = hsrc + (size_t)vt * ((size_t)S_TOT * RE);

  auto stageA = [&](int buf, int i) {
    int tap = i % 9, cpair = i / 9;
#pragma unroll
    for (int j2 = 0; j2 < 3; ++j2) {
      int u = wv * 3 + j2;
      int chunk = u / 6, grp = u % 6;
      int row = grp * 16 + (l >> 2);
      int segs = (l & 3) ^ ((row >> 1) & 3);
      const bf16_t* g = hb + (size_t)adjs[row * 9 + tap] * RE + cpair * 64 + chunk * 32 + segs * 8;
      gll16(g, &ab[buf][chunk][grp * 512]);
    }
  };

  auto asmB = [&](i32x4* dst, int i) {
    int tap = i % 9, cpair = i / 9;
    const bf16_t* pa = Wp + (size_t)(18 * cpair + tap) * 8192 + nw * 2048 + l * 8;
    const bf16_t* pb = pa + 9 * 8192;
    asm volatile(
        "global_load_dwordx4 %0, %4, off\n\t"
        "global_load_dwordx4 %1, %4, off offset:1024\n\t"
        "global_load_dwordx4 %2, %4, off offset:2048\n\t"
        "global_load_dwordx4 %3, %4, off offset:3072"
        : "=&v"(dst[0]), "=&v"(dst[1]), "=&v"(dst[2]), "=&v"(dst[3])
        : "v"(pa));
    asm volatile(
        "global_load_dwordx4 %0, %4, off\n\t"
        "global_load_dwordx4 %1, %4, off offset:1024\n\t"
        "global_load_dwordx4 %2, %4, off offset:2048\n\t"
        "global_load_dwordx4 %3, %4, off offset:3072"
        : "=&v"(dst[4]), "=&v"(dst[5]), "=&v"(dst[6]), "=&v"(dst[7])
        : "v"(pb));
  };

  auto asmBx = [&](i32x4* dst, int sx) {
    const bf16_t* pa = Wsp + (size_t)(2 * sx) * 8192 + nw * 2048 + l * 8;
    const bf16_t* pb = pa + 8192;
    asm volatile(
        "global_load_dwordx4 %0, %4, off\n\t"
        "global_load_dwordx4 %1, %4, off offset:1024\n\t"
        "global_load_dwordx4 %2, %4, off offset:2048\n\t"
        "global_load_dwordx4 %3, %4, off offset:3072"
        : "=&v"(dst[0]), "=&v"(dst[1]), "=&v"(dst[2]), "=&v"(dst[3])
        : "v"(pa));
    asm volatile(
        "global_load_dwordx4 %0, %4, off\n\t"
        "global_load_dwordx4 %1, %4, off offset:1024\n\t"
        "global_load_dwordx4 %2, %4, off offset:2048\n\t"
        "global_load_dwordx4 %3, %4, off offset:3072"
        : "=&v"(dst[4]), "=&v"(dst[5]), "=&v"(dst[6]), "=&v"(dst[7])
        : "v"(pb));
  };

  auto stageX = [&](int buf, int sx) {
#pragma unroll
    for (int j = 0; j < 3; ++j) {
      int idx = j * 256 + tid;
      int row = idx >> 3, rest = idx & 7;
      int sc = rest >> 2, q = rest & 3;
      const float* xr = x + ((size_t)vt * S_TOT + s0 + row) * F_IN + sx * 64 + sc * 32 + q * 8;
      f32x4 xv0 = *(const f32x4*)(xr);
      f32x4 xv1 = *(const f32x4*)(xr + 4);
      bf16x8 w;
#pragma unroll
      for (int jj = 0; jj < 4; ++jj) {
        w[jj] = (bf16_t)xv0[jj];
        w[4 + jj] = (bf16_t)xv1[jj];
      }
      *(bf16x8*)(&ab[buf][sc][row * 32 + ((q ^ ((row >> 1) & 3)) << 3)]) = w;
    }
  };

  f32x4 acc[6][4] = {};
  auto compute = [&](int buf, const i32x4* bv) {
    __builtin_amdgcn_s_setprio(1);
#pragma unroll
    for (int sc = 0; sc < 2; ++sc) {
#pragma unroll
      for (int mi = 0; mi < 6; ++mi) {
        int rr = mi * 16 + lo;
        bf16x8 afr = *(const bf16x8*)(&ab[buf][sc][rr * 32 + ((hi ^ ((rr >> 1) & 3)) << 3)]);
#pragma unroll
        for (int ni = 0; ni < 4; ++ni)
          acc[mi][ni] = __builtin_amdgcn_mfma_f32_16x16x32_bf16(
              afr, __builtin_bit_cast(bf16x8, bv[sc * 4 + ni]), acc[mi][ni], 0, 0, 0);
      }
    }
    __builtin_amdgcn_s_setprio(0);
  };

  i32x4 b0[8], b1[8];
  stageA(0, 0);
  asmB(b0, 0);
  stageA(1, 1);
  int bcur3 = 0, bstg3 = 2;

  for (int s = 0; s < NM64 - 2; s += 2) {
    asmB(b1, s + 1);
    asm volatile("s_waitcnt vmcnt(11)" ::: "memory");
    __builtin_amdgcn_s_barrier();
    __builtin_amdgcn_sched_barrier(0);
    stageA(bstg3, s + 2);
    compute(bcur3, b0);
    bcur3 = (bcur3 == 2) ? 0 : bcur3 + 1;
    bstg3 = (bstg3 == 2) ? 0 : bstg3 + 1;
    asmB(b0, s + 2);
    asm volatile("s_waitcnt vmcnt(11)" ::: "memory");
    __builtin_amdgcn_s_barrier();
    __builtin_amdgcn_sched_barrier(0);
    stageA(bstg3, s + 3);
    compute(bcur3, b1);
    bcur3 = (bcur3 == 2) ? 0 : bcur3 + 1;
    bstg3 = (bstg3 == 2) ? 0 : bstg3 + 1;
  }
  asmB(b1, NM64 - 1);
  asm volatile("s_waitcnt vmcnt(11)" ::: "memory");
  __builtin_amdgcn_s_barrier();
  __builtin_amdgcn_sched_barrier(0);
  compute(bcur3, b0);
  bcur3 = (bcur3 == 2) ? 0 : bcur3 + 1;
  asm volatile("s_waitcnt vmcnt(0)" ::: "memory");
  __builtin_amdgcn_s_barrier();
  __builtin_amdgcn_sched_barrier(0);
  compute(bcur3, b1);

  if (XSK) {
#pragma unroll
    for (int sx = 0; sx < 2; ++sx) {
      __syncthreads();
      stageX(sx, sx);
      if (sx) asmBx(b1, sx); else asmBx(b0, sx);
      asm volatile("s_waitcnt vmcnt(0)" ::: "memory");
      __syncthreads();
      __builtin_amdgcn_sched_barrier(0);
      compute(sx, sx ? (const i32x4*)b1 : (const i32x4*)b0);
    }
  }

  if (!XSK) {
    // ---- conv1 epilogue: stats from acc -> grid barrier -> apply -> store ----
    float bvv[4];
#pragma unroll
    for (int ni = 0; ni < 4; ++ni) {
      int o = nw * 64 + ni * 16 + lo;
      float bv = bias[o];
      bvv[ni] = bv;
      float s_ = 0.f, q_ = 0.f;
#pragma unroll
      for (int mi = 0; mi < 6; ++mi)
#pragma unroll
        for (int r2 = 0; r2 < 4; ++r2) {
          float v = acc[mi][ni][r2] + bv;
          s_ += v; q_ += v * v;
        }
      s_ += __shfl_xor(s_, 16); s_ += __shfl_xor(s_, 32);
      q_ += __shfl_xor(q_, 16); q_ += __shfl_xor(q_, 32);
      if (hi == 0) {
        atomicAdd(&sum_c[vt * 256 + o], s_);
        atomicAdd(&ss_c[vt * 256 + o], q_);
      }
    }
    grid_barrier(cnt, 512);
    // coeffs for all 256 channels into dead LDS (ab storage reused)
    float* aco = (float*)&ab[0][0][0];
    float* bco = aco + 256;
    {
      int c = tid;
      int g = c >> 3;
      float sg = 0.f, qg = 0.f;
#pragma unroll
      for (int j = 0; j < 8; ++j) {
        sg += sum_c[vt * 256 + g * 8 + j];
        qg += ss_c[vt * 256 + g * 8 + j];
      }
      float N = (float)(S_TOT * 8);
      float mean = sg / N;
      float var = qg / N - mean * mean;
      float r = rsqrtf(var + EPS);
      float a = r * g2s[c];
      aco[c] = a;
      bco[c] = g2b[c] - mean * a;
    }
    __syncthreads();
    bf16_t* ob = outb + ((size_t)vt * S_TOT + s0) * 256;
#pragma unroll
    for (int ni = 0; ni < 4; ++ni) {
      int o = nw * 64 + ni * 16 + lo;
      float a = aco[o], b = bco[o];
#pragma unroll
      for (int mi = 0; mi < 6; ++mi)
#pragma unroll
        for (int r2 = 0; r2 < 4; ++r2) {
          int srow = mi * 16 + hi * 4 + r2;
          float v = acc[mi][ni][r2] + bvv[ni];
          ob[(size_t)srow * 256 + o] = (bf16_t)silu_f(a * v + b);
        }
    }
  } else {
    float* of = outf + ((size_t)vt * S_TOT + s0) * 256;
#pragma unroll
    for (int ni = 0; ni < 4; ++ni) {
      int o = nw * 64 + ni * 16 + lo;
      float bv = bias[o] + biask[o];
#pragma unroll
      for (int mi = 0; mi < 6; ++mi)
#pragma unroll
        for (int r2 = 0; r2 < 4; ++r2) {
          int srow = mi * 16 + hi * 4 + r2;
          of[(size_t)srow * 256 + o] = acc[mi][ni][r2] + bv;
        }
    }
  }
}

extern "C" void kernel_launch(void* const* d_in, const int* in_sizes, int n_in,
                              void* d_out, int out_size, void* d_ws, size_t ws_size,
                              hipStream_t stream) {
  const float* x      = (const float*)d_in[0];
  const int*   adjc   = (const int*)d_in[1];
  const float* gn1_s  = (const float*)d_in[2];
  const float* gn1_b  = (const float*)d_in[3];
  const float* gn2_s  = (const float*)d_in[4];
  const float* gn2_b  = (const float*)d_in[5];
  const float* W_skip = (const float*)d_in[6];
  const float* b_skip = (const float*)d_in[7];
  const float* W1     = (const float*)d_in[8];
  const float* b1     = (const float*)d_in[9];
  const float* W2     = (const float*)d_in[10];
  const float* b2     = (const float*)d_in[11];
  float* out = (float*)d_out;

  float* sum1  = (float*)d_ws;           // 128
  float* ss1   = sum1 + 128;             // 128
  float* sum_c = ss1 + 128;              // 1024
  float* ss_c  = sum_c + 1024;           // 1024
  int*   cnts  = (int*)(ss_c + 1024);    // 2 counters (in pad region)
  float* pad   = ss_c + 1024;            // 3072 (layout pad incl counters)
  bf16_t* W1p  = (bf16_t*)(pad + 3072);  // 294912
  bf16_t* W2p  = W1p + 294912;           // 589824
  bf16_t* Wsp  = W2p + 589824;           // 32768
  bf16_t* h1   = Wsp + 32768;            // 6291456
  bf16_t* out1 = h1 + 6291456;           // 12582912 (h2, applied in conv1)

  hipMemsetAsync(sum1, 0, (128 + 128 + 1024 + 1024 + 16) * sizeof(float), stream);
  fusedA<<<1216, 256, 0, stream>>>(W1, W2, W_skip, W1p, W2p, Wsp,
                                   x, sum1, ss1, gn1_s, gn1_b, h1, cnts);
  conv_kernel<128, 18, false><<<512, 256, 0, stream>>>(
      h1, W1p, nullptr, nullptr, adjc, b1, nullptr, out1, nullptr,
      sum_c, ss_c, gn2_s, gn2_b, cnts + 1);
  conv_kernel<256, 36, true><<<512, 256, 0, stream>>>(
      out1, W2p, Wsp, x, adjc, b2, b_skip, nullptr, out,
      nullptr, nullptr, nullptr, nullptr, nullptr);
}

// Round 16
// 177.075 us; speedup vs baseline: 1.4625x; 1.4625x over previous
//
#include <hip/hip_runtime.h>
#include <hip/hip_bf16.h>

typedef __bf16 bf16_t;
typedef __bf16 bf16x8 __attribute__((ext_vector_type(8)));
typedef float f32x4 __attribute__((ext_vector_type(4)));
typedef int i32x4 __attribute__((ext_vector_type(4)));

#define S_TOT 12288
#define F_IN 128
#define F_OUT 256
#define EPS 1e-5f

static __device__ __forceinline__ float silu_f(float v) {
  return v / (1.0f + __expf(-v));
}

static __device__ __forceinline__ void gll16(const bf16_t* g, bf16_t* l) {
  __builtin_amdgcn_global_load_lds(
      (const __attribute__((address_space(1))) void*)(const void*)g,
      (__attribute__((address_space(3))) void*)(void*)l, 16, 0, 0);
}

// Device-scope spin barrier. SAFE ONLY for uniform grids at exact co-residency
// (conv1: 512 blocks = exactly 2/CU, all resident from t=0, identical work).
static __device__ __forceinline__ void grid_barrier(int* cnt, int n) {
  __syncthreads();
  if (threadIdx.x == 0) {
    __threadfence();   // release
    __hip_atomic_fetch_add(cnt, 1, __ATOMIC_ACQ_REL, __HIP_MEMORY_SCOPE_AGENT);
    while (__hip_atomic_load(cnt, __ATOMIC_ACQUIRE, __HIP_MEMORY_SCOPE_AGENT) < n)
      __builtin_amdgcn_s_sleep(2);
    __threadfence();   // acquire
  }
  __syncthreads();
}

// ---------------- prep: pack weights (blocks 0..447) + GN1 stats (448..639) ----
// CHUNK-MAJOR pack: kcg = chunk*9 + tap. Unit (kcg, cb): lane l holds
// B[f=32*chunk+8*(l>>4)+j of W_tap][o=16cb+(l&15)] at unit*1024B + l*16B.
__global__ void prep_kernel(const float* __restrict__ W1,
                            const float* __restrict__ W2,
                            const float* __restrict__ Wsk,
                            bf16_t* __restrict__ W1p,
                            bf16_t* __restrict__ W2p,
                            bf16_t* __restrict__ Wsp,
                            const float* __restrict__ x,
                            float* __restrict__ sum1, float* __restrict__ ss1) {
  __shared__ float gs[32], gq[32];
  if (blockIdx.x < 448) {
    int w = blockIdx.x * 4 + (threadIdx.x >> 6);
    int l = threadIdx.x & 63;
    int lo = l & 15, hi = l >> 4;
    const float* src;
    bf16_t* dst;
    int fbase, obase;
    if (w < 576) {
      int kcg = w >> 4, cb = w & 15;
      int tap = kcg % 9, chunk = kcg / 9;
      src = W1 + tap * 32768;
      dst = W1p + (size_t)w * 512;
      fbase = 32 * chunk + 8 * hi; obase = 16 * cb + lo;
    } else if (w < 1728) {
      int idx = w - 576;
      int kcg = idx >> 4, cb = idx & 15;
      int tap = kcg % 9, chunk = kcg / 9;
      src = W2 + tap * 65536;
      dst = W2p + (size_t)idx * 512;
      fbase = 32 * chunk + 8 * hi; obase = 16 * cb + lo;
    } else {
      int idx = w - 1728;
      int kc = idx >> 4, cb = idx & 15;
      src = Wsk;
      dst = Wsp + (size_t)idx * 512;
      fbase = 32 * kc + 8 * hi; obase = 16 * cb + lo;
    }
    bf16x8 v;
#pragma unroll
    for (int j = 0; j < 8; ++j)
      v[j] = (bf16_t)src[(fbase + j) * 256 + obase];
    *(bf16x8*)(dst + l * 8) = v;
  } else {
    int blk = blockIdx.x - 448;
    int vt = blk & 3;
    int s0 = (blk >> 2) * 256;
    int t = threadIdx.x;
    int col = t & 31, ro = t >> 5;
    float s_ = 0.f, q_ = 0.f;
    const f32x4* xp = (const f32x4*)(x + ((size_t)vt * S_TOT + s0) * F_IN);
#pragma unroll 4
    for (int it = 0; it < 32; ++it) {
      f32x4 v = xp[(size_t)(it * 8 + ro) * 32 + col];
      s_ += v[0] + v[1] + v[2] + v[3];
      q_ += v[0]*v[0] + v[1]*v[1] + v[2]*v[2] + v[3]*v[3];
    }
    if (t < 32) { gs[t] = 0.f; gq[t] = 0.f; }
    __syncthreads();
    atomicAdd(&gs[col], s_);
    atomicAdd(&gq[col], q_);
    __syncthreads();
    if (t < 32) {
      atomicAdd(&sum1[vt * 32 + t], gs[t]);
      atomicAdd(&ss1[vt * 32 + t], gq[t]);
    }
  }
}

// ---------------- apply GN1 + SiLU -> h1 (block-level coeffs in LDS) ----------
__global__ void apply_gn1(const float* __restrict__ x,
                          const float* __restrict__ sum1, const float* __restrict__ ss1,
                          const float* __restrict__ gs, const float* __restrict__ gb,
                          bf16_t* __restrict__ h1) {
  __shared__ float aco[128], bco[128];
  int blk = blockIdx.x;
  int vt = blk / 192;
  size_t base = (size_t)blk * 8192;
  int t = threadIdx.x;
  if (t < 32) {
    float N = (float)(S_TOT * 4);
    float mean = sum1[vt * 32 + t] / N;
    float var = ss1[vt * 32 + t] / N - mean * mean;
    float r = rsqrtf(var + EPS);
#pragma unroll
    for (int j = 0; j < 4; ++j) {
      int c = t * 4 + j;
      float a = r * gs[c];
      aco[c] = a;
      bco[c] = gb[c] - mean * a;
    }
  }
  __syncthreads();
  int c0 = (t * 8) & 127;
  f32x4 A0 = *(const f32x4*)&aco[c0];
  f32x4 A1 = *(const f32x4*)&aco[c0 + 4];
  f32x4 B0 = *(const f32x4*)&bco[c0];
  f32x4 B1 = *(const f32x4*)&bco[c0 + 4];
#pragma unroll
  for (int i = 0; i < 4; ++i) {
    size_t idx = base + (size_t)i * 2048 + t * 8;
    const f32x4* xp = (const f32x4*)(x + idx);
    f32x4 v0 = xp[0], v1 = xp[1];
    bf16x8 o;
#pragma unroll
    for (int j = 0; j < 4; ++j) o[j] = (bf16_t)silu_f(v0[j] * A0[j] + B0[j]);
#pragma unroll
    for (int j = 0; j < 4; ++j) o[4 + j] = (bf16_t)silu_f(v1[j] * A1[j] + B1[j]);
    *(bf16x8*)(h1 + idx) = o;
  }
}

// ---------------- unified gather-conv GEMM (v13 core) ----------------
// Block 96 rows x 256 cols, 4 waves of 96x64, acc[6][4]. Grid 512 = 2 blocks/CU.
// K64 per barrier; ring-3 A via gll; B 8 asm dwordx4 reg-dbuf; steady vmcnt(11).
// !XSK (conv1): fused epilogue = GN2 stats from acc -> grid_barrier (512 blocks,
// uniform work, all co-resident) -> coeffs in dead LDS -> SiLU(affine(acc)) ->
// single bf16 store of h2. XSK (conv2): f32 out + skip tail (unchanged).
template<int RE, int NM64, bool XSK>
__global__ __launch_bounds__(256, 2) void conv_kernel(
    const bf16_t* __restrict__ hsrc, const bf16_t* __restrict__ Wp,
    const bf16_t* __restrict__ Wsp, const float* __restrict__ x,
    const int* __restrict__ adjc, const float* __restrict__ bias,
    const float* __restrict__ biask, bf16_t* __restrict__ outb,
    float* __restrict__ outf, float* __restrict__ sum_c, float* __restrict__ ss_c,
    const float* __restrict__ g2s, const float* __restrict__ g2b,
    int* __restrict__ cnt) {
  const int tid = threadIdx.x;
  const int wv = tid >> 6, l = tid & 63;
  const int lo = l & 15, hi = l >> 4;
  const int nw = wv;

  int swz = ((blockIdx.x & 7) << 6) + (blockIdx.x >> 3);   // bijective: 512 = 8*64
  int vt = swz >> 7;
  int rem = swz & 127;
  int s0 = rem * 96;

  __shared__ int adjs[864];
  __shared__ bf16_t ab[3][2][3072];   // ring-3, 2 chunks, 96 rows x 32 (64B rows)

  for (int i = tid; i < 864; i += 256) adjs[i] = adjc[s0 * 9 + i];
  __syncthreads();

  const bf16_t* hb = hsrc + (size_t)vt * ((size_t)S_TOT * RE);

  auto stageA = [&](int buf, int i) {
    int tap = i % 9, cpair = i / 9;
#pragma unroll
    for (int j2 = 0; j2 < 3; ++j2) {
      int u = wv * 3 + j2;
      int chunk = u / 6, grp = u % 6;
      int row = grp * 16 + (l >> 2);
      int segs = (l & 3) ^ ((row >> 1) & 3);
      const bf16_t* g = hb + (size_t)adjs[row * 9 + tap] * RE + cpair * 64 + chunk * 32 + segs * 8;
      gll16(g, &ab[buf][chunk][grp * 512]);
    }
  };

  auto asmB = [&](i32x4* dst, int i) {
    int tap = i % 9, cpair = i / 9;
    const bf16_t* pa = Wp + (size_t)(18 * cpair + tap) * 8192 + nw * 2048 + l * 8;
    const bf16_t* pb = pa + 9 * 8192;
    asm volatile(
        "global_load_dwordx4 %0, %4, off\n\t"
        "global_load_dwordx4 %1, %4, off offset:1024\n\t"
        "global_load_dwordx4 %2, %4, off offset:2048\n\t"
        "global_load_dwordx4 %3, %4, off offset:3072"
        : "=&v"(dst[0]), "=&v"(dst[1]), "=&v"(dst[2]), "=&v"(dst[3])
        : "v"(pa));
    asm volatile(
        "global_load_dwordx4 %0, %4, off\n\t"
        "global_load_dwordx4 %1, %4, off offset:1024\n\t"
        "global_load_dwordx4 %2, %4, off offset:2048\n\t"
        "global_load_dwordx4 %3, %4, off offset:3072"
        : "=&v"(dst[4]), "=&v"(dst[5]), "=&v"(dst[6]), "=&v"(dst[7])
        : "v"(pb));
  };

  auto asmBx = [&](i32x4* dst, int sx) {
    const bf16_t* pa = Wsp + (size_t)(2 * sx) * 8192 + nw * 2048 + l * 8;
    const bf16_t* pb = pa + 8192;
    asm volatile(
        "global_load_dwordx4 %0, %4, off\n\t"
        "global_load_dwordx4 %1, %4, off offset:1024\n\t"
        "global_load_dwordx4 %2, %4, off offset:2048\n\t"
        "global_load_dwordx4 %3, %4, off offset:3072"
        : "=&v"(dst[0]), "=&v"(dst[1]), "=&v"(dst[2]), "=&v"(dst[3])
        : "v"(pa));
    asm volatile(
        "global_load_dwordx4 %0, %4, off\n\t"
        "global_load_dwordx4 %1, %4, off offset:1024\n\t"
        "global_load_dwordx4 %2, %4, off offset:2048\n\t"
        "global_load_dwordx4 %3, %4, off offset:3072"
        : "=&v"(dst[4]), "=&v"(dst[5]), "=&v"(dst[6]), "=&v"(dst[7])
        : "v"(pb));
  };

  auto stageX = [&](int buf, int sx) {
#pragma unroll
    for (int j = 0; j < 3; ++j) {
      int idx = j * 256 + tid;
      int row = idx >> 3, rest = idx & 7;
      int sc = rest >> 2, q = rest & 3;
      const float* xr = x + ((size_t)vt * S_TOT + s0 + row) * F_IN + sx * 64 + sc * 32 + q * 8;
      f32x4 xv0 = *(const f32x4*)(xr);
      f32x4 xv1 = *(const f32x4*)(xr + 4);
      bf16x8 w;
#pragma unroll
      for (int jj = 0; jj < 4; ++jj) {
        w[jj] = (bf16_t)xv0[jj];
        w[4 + jj] = (bf16_t)xv1[jj];
      }
      *(bf16x8*)(&ab[buf][sc][row * 32 + ((q ^ ((row >> 1) & 3)) << 3)]) = w;
    }
  };

  f32x4 acc[6][4] = {};
  auto compute = [&](int buf, const i32x4* bv) {
    __builtin_amdgcn_s_setprio(1);
#pragma unroll
    for (int sc = 0; sc < 2; ++sc) {
#pragma unroll
      for (int mi = 0; mi < 6; ++mi) {
        int rr = mi * 16 + lo;
        bf16x8 afr = *(const bf16x8*)(&ab[buf][sc][rr * 32 + ((hi ^ ((rr >> 1) & 3)) << 3)]);
#pragma unroll
        for (int ni = 0; ni < 4; ++ni)
          acc[mi][ni] = __builtin_amdgcn_mfma_f32_16x16x32_bf16(
              afr, __builtin_bit_cast(bf16x8, bv[sc * 4 + ni]), acc[mi][ni], 0, 0, 0);
      }
    }
    __builtin_amdgcn_s_setprio(0);
  };

  i32x4 b0[8], b1[8];
  stageA(0, 0);
  asmB(b0, 0);
  stageA(1, 1);
  int bcur3 = 0, bstg3 = 2;

  for (int s = 0; s < NM64 - 2; s += 2) {
    asmB(b1, s + 1);
    asm volatile("s_waitcnt vmcnt(11)" ::: "memory");
    __builtin_amdgcn_s_barrier();
    __builtin_amdgcn_sched_barrier(0);
    stageA(bstg3, s + 2);
    compute(bcur3, b0);
    bcur3 = (bcur3 == 2) ? 0 : bcur3 + 1;
    bstg3 = (bstg3 == 2) ? 0 : bstg3 + 1;
    asmB(b0, s + 2);
    asm volatile("s_waitcnt vmcnt(11)" ::: "memory");
    __builtin_amdgcn_s_barrier();
    __builtin_amdgcn_sched_barrier(0);
    stageA(bstg3, s + 3);
    compute(bcur3, b1);
    bcur3 = (bcur3 == 2) ? 0 : bcur3 + 1;
    bstg3 = (bstg3 == 2) ? 0 : bstg3 + 1;
  }
  asmB(b1, NM64 - 1);
  asm volatile("s_waitcnt vmcnt(11)" ::: "memory");
  __builtin_amdgcn_s_barrier();
  __builtin_amdgcn_sched_barrier(0);
  compute(bcur3, b0);
  bcur3 = (bcur3 == 2) ? 0 : bcur3 + 1;
  asm volatile("s_waitcnt vmcnt(0)" ::: "memory");
  __builtin_amdgcn_s_barrier();
  __builtin_amdgcn_sched_barrier(0);
  compute(bcur3, b1);

  if (XSK) {
#pragma unroll
    for (int sx = 0; sx < 2; ++sx) {
      __syncthreads();
      stageX(sx, sx);
      if (sx) asmBx(b1, sx); else asmBx(b0, sx);
      asm volatile("s_waitcnt vmcnt(0)" ::: "memory");
      __syncthreads();
      __builtin_amdgcn_sched_barrier(0);
      compute(sx, sx ? (const i32x4*)b1 : (const i32x4*)b0);
    }
  }

  if (!XSK) {
    // ---- fused epilogue: GN2 stats -> grid barrier -> apply -> single store ----
    float bvv[4];
#pragma unroll
    for (int ni = 0; ni < 4; ++ni) {
      int o = nw * 64 + ni * 16 + lo;
      float bv = bias[o];
      bvv[ni] = bv;
      float s_ = 0.f, q_ = 0.f;
#pragma unroll
      for (int mi = 0; mi < 6; ++mi)
#pragma unroll
        for (int r2 = 0; r2 < 4; ++r2) {
          float v = acc[mi][ni][r2] + bv;
          s_ += v; q_ += v * v;
        }
      s_ += __shfl_xor(s_, 16); s_ += __shfl_xor(s_, 32);
      q_ += __shfl_xor(q_, 16); q_ += __shfl_xor(q_, 32);
      if (hi == 0) {
        atomicAdd(&sum_c[vt * 256 + o], s_);
        atomicAdd(&ss_c[vt * 256 + o], q_);
      }
    }
    grid_barrier(cnt, 512);
    float* aco = (float*)&ab[0][0][0];
    float* bco = aco + 256;
    {
      int c = tid;
      int g = c >> 3;
      float sg = 0.f, qg = 0.f;
#pragma unroll
      for (int j = 0; j < 8; ++j) {
        sg += sum_c[vt * 256 + g * 8 + j];
        qg += ss_c[vt * 256 + g * 8 + j];
      }
      float N = (float)(S_TOT * 8);
      float mean = sg / N;
      float var = qg / N - mean * mean;
      float r = rsqrtf(var + EPS);
      float a = r * g2s[c];
      aco[c] = a;
      bco[c] = g2b[c] - mean * a;
    }
    __syncthreads();
    bf16_t* ob = outb + ((size_t)vt * S_TOT + s0) * 256;
#pragma unroll
    for (int ni = 0; ni < 4; ++ni) {
      int o = nw * 64 + ni * 16 + lo;
      float a = aco[o], b = bco[o];
#pragma unroll
      for (int mi = 0; mi < 6; ++mi)
#pragma unroll
        for (int r2 = 0; r2 < 4; ++r2) {
          int srow = mi * 16 + hi * 4 + r2;
          float v = acc[mi][ni][r2] + bvv[ni];
          ob[(size_t)srow * 256 + o] = (bf16_t)silu_f(a * v + b);
        }
    }
  } else {
    float* of = outf + ((size_t)vt * S_TOT + s0) * 256;
#pragma unroll
    for (int ni = 0; ni < 4; ++ni) {
      int o = nw * 64 + ni * 16 + lo;
      float bv = bias[o] + biask[o];
#pragma unroll
      for (int mi = 0; mi < 6; ++mi)
#pragma unroll
        for (int r2 = 0; r2 < 4; ++r2) {
          int srow = mi * 16 + hi * 4 + r2;
          of[(size_t)srow * 256 + o] = acc[mi][ni][r2] + bv;
        }
    }
  }
}

extern "C" void kernel_launch(void* const* d_in, const int* in_sizes, int n_in,
                              void* d_out, int out_size, void* d_ws, size_t ws_size,
                              hipStream_t stream) {
  const float* x      = (const float*)d_in[0];
  const int*   adjc   = (const int*)d_in[1];
  const float* gn1_s  = (const float*)d_in[2];
  const float* gn1_b  = (const float*)d_in[3];
  const float* gn2_s  = (const float*)d_in[4];
  const float* gn2_b  = (const float*)d_in[5];
  const float* W_skip = (const float*)d_in[6];
  const float* b_skip = (const float*)d_in[7];
  const float* W1     = (const float*)d_in[8];
  const float* b1     = (const float*)d_in[9];
  const float* W2     = (const float*)d_in[10];
  const float* b2     = (const float*)d_in[11];
  float* out = (float*)d_out;

  float* sum1  = (float*)d_ws;           // 128
  float* ss1   = sum1 + 128;             // 128
  float* sum_c = ss1 + 128;              // 1024
  float* ss_c  = sum_c + 1024;           // 1024
  int*   cnts  = (int*)(ss_c + 1024);    // counters (in pad region)
  float* pad   = ss_c + 1024;            // 3072 (layout pad incl counters)
  bf16_t* W1p  = (bf16_t*)(pad + 3072);  // 294912
  bf16_t* W2p  = W1p + 294912;           // 589824
  bf16_t* Wsp  = W2p + 589824;           // 32768
  bf16_t* h1   = Wsp + 32768;            // 6291456
  bf16_t* out1 = h1 + 6291456;           // 12582912 (h2, applied in conv1)

  hipMemsetAsync(sum1, 0, (128 + 128 + 1024 + 1024 + 16) * sizeof(float), stream);
  prep_kernel<<<640, 256, 0, stream>>>(W1, W2, W_skip, W1p, W2p, Wsp, x, sum1, ss1);
  apply_gn1<<<768, 256, 0, stream>>>(x, sum1, ss1, gn1_s, gn1_b, h1);
  conv_kernel<128, 18, false><<<512, 256, 0, stream>>>(
      h1, W1p, nullptr, nullptr, adjc, b1, nullptr, out1, nullptr,
      sum_c, ss_c, gn2_s, gn2_b, cnts);
  conv_kernel<256, 36, true><<<512, 256, 0, stream>>>(
      out1, W2p, Wsp, x, adjc, b2, b_skip, nullptr, out,
      nullptr, nullptr, nullptr, nullptr, nullptr);
}

// Round 17
// 128.688 us; speedup vs baseline: 2.0124x; 1.3760x over previous
//
#include <hip/hip_runtime.h>
#include <hip/hip_bf16.h>

typedef __bf16 bf16_t;
typedef __bf16 bf16x8 __attribute__((ext_vector_type(8)));
typedef float f32x4 __attribute__((ext_vector_type(4)));
typedef int i32x4 __attribute__((ext_vector_type(4)));

#define S_TOT 12288
#define F_IN 128
#define F_OUT 256
#define EPS 1e-5f

static __device__ __forceinline__ float silu_f(float v) {
  return v / (1.0f + __expf(-v));
}

static __device__ __forceinline__ void gll16(const bf16_t* g, bf16_t* l) {
  __builtin_amdgcn_global_load_lds(
      (const __attribute__((address_space(1))) void*)(const void*)g,
      (__attribute__((address_space(3))) void*)(void*)l, 16, 0, 0);
}

// ---------------- prep: pack weights (blocks 0..447) + GN1 stats (448..639) ----
// CHUNK-MAJOR pack: kcg = chunk*9 + tap. Unit (kcg, cb): lane l holds
// B[f=32*chunk+8*(l>>4)+j of W_tap][o=16cb+(l&15)] at unit*1024B + l*16B.
__global__ void prep_kernel(const float* __restrict__ W1,
                            const float* __restrict__ W2,
                            const float* __restrict__ Wsk,
                            bf16_t* __restrict__ W1p,
                            bf16_t* __restrict__ W2p,
                            bf16_t* __restrict__ Wsp,
                            const float* __restrict__ x,
                            float* __restrict__ sum1, float* __restrict__ ss1) {
  __shared__ float gs[32], gq[32];
  if (blockIdx.x < 448) {
    int w = blockIdx.x * 4 + (threadIdx.x >> 6);
    int l = threadIdx.x & 63;
    int lo = l & 15, hi = l >> 4;
    const float* src;
    bf16_t* dst;
    int fbase, obase;
    if (w < 576) {
      int kcg = w >> 4, cb = w & 15;
      int tap = kcg % 9, chunk = kcg / 9;
      src = W1 + tap * 32768;
      dst = W1p + (size_t)w * 512;
      fbase = 32 * chunk + 8 * hi; obase = 16 * cb + lo;
    } else if (w < 1728) {
      int idx = w - 576;
      int kcg = idx >> 4, cb = idx & 15;
      int tap = kcg % 9, chunk = kcg / 9;
      src = W2 + tap * 65536;
      dst = W2p + (size_t)idx * 512;
      fbase = 32 * chunk + 8 * hi; obase = 16 * cb + lo;
    } else {
      int idx = w - 1728;
      int kc = idx >> 4, cb = idx & 15;
      src = Wsk;
      dst = Wsp + (size_t)idx * 512;
      fbase = 32 * kc + 8 * hi; obase = 16 * cb + lo;
    }
    bf16x8 v;
#pragma unroll
    for (int j = 0; j < 8; ++j)
      v[j] = (bf16_t)src[(fbase + j) * 256 + obase];
    *(bf16x8*)(dst + l * 8) = v;
  } else {
    int blk = blockIdx.x - 448;
    int vt = blk & 3;
    int s0 = (blk >> 2) * 256;
    int t = threadIdx.x;
    int col = t & 31, ro = t >> 5;
    float s_ = 0.f, q_ = 0.f;
    const f32x4* xp = (const f32x4*)(x + ((size_t)vt * S_TOT + s0) * F_IN);
#pragma unroll 4
    for (int it = 0; it < 32; ++it) {
      f32x4 v = xp[(size_t)(it * 8 + ro) * 32 + col];
      s_ += v[0] + v[1] + v[2] + v[3];
      q_ += v[0]*v[0] + v[1]*v[1] + v[2]*v[2] + v[3]*v[3];
    }
    if (t < 32) { gs[t] = 0.f; gq[t] = 0.f; }
    __syncthreads();
    atomicAdd(&gs[col], s_);
    atomicAdd(&gq[col], q_);
    __syncthreads();
    if (t < 32) {
      atomicAdd(&sum1[vt * 32 + t], gs[t]);
      atomicAdd(&ss1[vt * 32 + t], gq[t]);
    }
  }
}

// ---------------- apply GN1 + SiLU -> h1 (block-level coeffs in LDS) ----------
// 768 blocks x 256 thr x 32 elems. Block = 8192 f32 = 64 rows x 128 ch, one vt.
__global__ void apply_gn1(const float* __restrict__ x,
                          const float* __restrict__ sum1, const float* __restrict__ ss1,
                          const float* __restrict__ gs, const float* __restrict__ gb,
                          bf16_t* __restrict__ h1) {
  __shared__ float aco[128], bco[128];
  int blk = blockIdx.x;
  int vt = blk / 192;
  size_t base = (size_t)blk * 8192;
  int t = threadIdx.x;
  if (t < 32) {
    float N = (float)(S_TOT * 4);
    float mean = sum1[vt * 32 + t] / N;
    float var = ss1[vt * 32 + t] / N - mean * mean;
    float r = rsqrtf(var + EPS);
#pragma unroll
    for (int j = 0; j < 4; ++j) {
      int c = t * 4 + j;
      float a = r * gs[c];
      aco[c] = a;
      bco[c] = gb[c] - mean * a;
    }
  }
  __syncthreads();
  int c0 = (t * 8) & 127;
  f32x4 A0 = *(const f32x4*)&aco[c0];
  f32x4 A1 = *(const f32x4*)&aco[c0 + 4];
  f32x4 B0 = *(const f32x4*)&bco[c0];
  f32x4 B1 = *(const f32x4*)&bco[c0 + 4];
#pragma unroll
  for (int i = 0; i < 4; ++i) {
    size_t idx = base + (size_t)i * 2048 + t * 8;
    const f32x4* xp = (const f32x4*)(x + idx);
    f32x4 v0 = xp[0], v1 = xp[1];
    bf16x8 o;
#pragma unroll
    for (int j = 0; j < 4; ++j) o[j] = (bf16_t)silu_f(v0[j] * A0[j] + B0[j]);
#pragma unroll
    for (int j = 0; j < 4; ++j) o[4 + j] = (bf16_t)silu_f(v1[j] * A1[j] + B1[j]);
    *(bf16x8*)(h1 + idx) = o;
  }
}

// ---------------- apply GN2 + SiLU in place (block-level coeffs in LDS) ------
// 1536 blocks x 256 thr x 32 elems. Block = 8192 bf16 = 32 rows x 256 ch.
__global__ void apply_gn2(bf16_t* __restrict__ h,
                          const float* __restrict__ sum_c, const float* __restrict__ ss_c,
                          const float* __restrict__ gs, const float* __restrict__ gb) {
  __shared__ float aco[256], bco[256];
  int blk = blockIdx.x;
  int vt = blk / 384;
  size_t base = (size_t)blk * 8192;
  int t = threadIdx.x;
  {
    int c = t;                         // thread t computes channel t's coeffs
    int g = c >> 3;
    float sg = 0.f, qg = 0.f;
#pragma unroll
    for (int j = 0; j < 8; ++j) {
      sg += sum_c[vt * 256 + g * 8 + j];
      qg += ss_c[vt * 256 + g * 8 + j];
    }
    float N = (float)(S_TOT * 8);
    float mean = sg / N;
    float var = qg / N - mean * mean;
    float r = rsqrtf(var + EPS);
    float a = r * gs[c];
    aco[c] = a;
    bco[c] = gb[c] - mean * a;
  }
  __syncthreads();
  int c0 = (t * 8) & 255;
  f32x4 A0 = *(const f32x4*)&aco[c0];
  f32x4 A1 = *(const f32x4*)&aco[c0 + 4];
  f32x4 B0 = *(const f32x4*)&bco[c0];
  f32x4 B1 = *(const f32x4*)&bco[c0 + 4];
#pragma unroll
  for (int i = 0; i < 4; ++i) {
    size_t idx = base + (size_t)i * 2048 + t * 8;
    bf16x8 v = *(const bf16x8*)(h + idx);
    bf16x8 o;
#pragma unroll
    for (int j = 0; j < 4; ++j) o[j] = (bf16_t)silu_f((float)v[j] * A0[j] + B0[j]);
#pragma unroll
    for (int j = 0; j < 4; ++j) o[4 + j] = (bf16_t)silu_f((float)v[4 + j] * A1[j] + B1[j]);
    *(bf16x8*)(h + idx) = o;
  }
}

// ---------------- unified gather-conv GEMM v13 (unchanged) ----------------
// Block 96 rows x 256 cols, 4 waves of 96x64, acc[6][4]. Grid 512 = 2 blocks/CU.
// K64 per barrier; ring-3 A via gll; B 8 asm dwordx4 reg-dbuf; steady vmcnt(11).
template<int RE, int NM64, bool XSK>
__global__ __launch_bounds__(256, 2) void conv_kernel(
    const bf16_t* __restrict__ hsrc, const bf16_t* __restrict__ Wp,
    const bf16_t* __restrict__ Wsp, const float* __restrict__ x,
    const int* __restrict__ adjc, const float* __restrict__ bias,
    const float* __restrict__ biask, bf16_t* __restrict__ outb,
    float* __restrict__ outf, float* __restrict__ sum_c, float* __restrict__ ss_c) {
  const int tid = threadIdx.x;
  const int wv = tid >> 6, l = tid & 63;
  const int lo = l & 15, hi = l >> 4;
  const int nw = wv;

  int swz = ((blockIdx.x & 7) << 6) + (blockIdx.x >> 3);   // bijective: 512 = 8*64
  int vt = swz >> 7;
  int rem = swz & 127;
  int s0 = rem * 96;

  __shared__ int adjs[864];
  __shared__ bf16_t ab[3][2][3072];   // ring-3, 2 chunks, 96 rows x 32 (64B rows)

  for (int i = tid; i < 864; i += 256) adjs[i] = adjc[s0 * 9 + i];
  __syncthreads();

  const bf16_t* hb = hsrc + (size_t)vt * ((size_t)S_TOT * RE);

  auto stageA = [&](int buf, int i) {
    int tap = i % 9, cpair = i / 9;
#pragma unroll
    for (int j2 = 0; j2 < 3; ++j2) {
      int u = wv * 3 + j2;
      int chunk = u / 6, grp = u % 6;
      int row = grp * 16 + (l >> 2);
      int segs = (l & 3) ^ ((row >> 1) & 3);
      const bf16_t* g = hb + (size_t)adjs[row * 9 + tap] * RE + cpair * 64 + chunk * 32 + segs * 8;
      gll16(g, &ab[buf][chunk][grp * 512]);
    }
  };

  auto asmB = [&](i32x4* dst, int i) {
    int tap = i % 9, cpair = i / 9;
    const bf16_t* pa = Wp + (size_t)(18 * cpair + tap) * 8192 + nw * 2048 + l * 8;
    const bf16_t* pb = pa + 9 * 8192;
    asm volatile(
        "global_load_dwordx4 %0, %4, off\n\t"
        "global_load_dwordx4 %1, %4, off offset:1024\n\t"
        "global_load_dwordx4 %2, %4, off offset:2048\n\t"
        "global_load_dwordx4 %3, %4, off offset:3072"
        : "=&v"(dst[0]), "=&v"(dst[1]), "=&v"(dst[2]), "=&v"(dst[3])
        : "v"(pa));
    asm volatile(
        "global_load_dwordx4 %0, %4, off\n\t"
        "global_load_dwordx4 %1, %4, off offset:1024\n\t"
        "global_load_dwordx4 %2, %4, off offset:2048\n\t"
        "global_load_dwordx4 %3, %4, off offset:3072"
        : "=&v"(dst[4]), "=&v"(dst[5]), "=&v"(dst[6]), "=&v"(dst[7])
        : "v"(pb));
  };

  auto asmBx = [&](i32x4* dst, int sx) {
    const bf16_t* pa = Wsp + (size_t)(2 * sx) * 8192 + nw * 2048 + l * 8;
    const bf16_t* pb = pa + 8192;
    asm volatile(
        "global_load_dwordx4 %0, %4, off\n\t"
        "global_load_dwordx4 %1, %4, off offset:1024\n\t"
        "global_load_dwordx4 %2, %4, off offset:2048\n\t"
        "global_load_dwordx4 %3, %4, off offset:3072"
        : "=&v"(dst[0]), "=&v"(dst[1]), "=&v"(dst[2]), "=&v"(dst[3])
        : "v"(pa));
    asm volatile(
        "global_load_dwordx4 %0, %4, off\n\t"
        "global_load_dwordx4 %1, %4, off offset:1024\n\t"
        "global_load_dwordx4 %2, %4, off offset:2048\n\t"
        "global_load_dwordx4 %3, %4, off offset:3072"
        : "=&v"(dst[4]), "=&v"(dst[5]), "=&v"(dst[6]), "=&v"(dst[7])
        : "v"(pb));
  };

  auto stageX = [&](int buf, int sx) {
#pragma unroll
    for (int j = 0; j < 3; ++j) {
      int idx = j * 256 + tid;
      int row = idx >> 3, rest = idx & 7;
      int sc = rest >> 2, q = rest & 3;
      const float* xr = x + ((size_t)vt * S_TOT + s0 + row) * F_IN + sx * 64 + sc * 32 + q * 8;
      f32x4 xv0 = *(const f32x4*)(xr);
      f32x4 xv1 = *(const f32x4*)(xr + 4);
      bf16x8 w;
#pragma unroll
      for (int jj = 0; jj < 4; ++jj) {
        w[jj] = (bf16_t)xv0[jj];
        w[4 + jj] = (bf16_t)xv1[jj];
      }
      *(bf16x8*)(&ab[buf][sc][row * 32 + ((q ^ ((row >> 1) & 3)) << 3)]) = w;
    }
  };

  f32x4 acc[6][4] = {};
  auto compute = [&](int buf, const i32x4* bv) {
    __builtin_amdgcn_s_setprio(1);
#pragma unroll
    for (int sc = 0; sc < 2; ++sc) {
#pragma unroll
      for (int mi = 0; mi < 6; ++mi) {
        int rr = mi * 16 + lo;
        bf16x8 afr = *(const bf16x8*)(&ab[buf][sc][rr * 32 + ((hi ^ ((rr >> 1) & 3)) << 3)]);
#pragma unroll
        for (int ni = 0; ni < 4; ++ni)
          acc[mi][ni] = __builtin_amdgcn_mfma_f32_16x16x32_bf16(
              afr, __builtin_bit_cast(bf16x8, bv[sc * 4 + ni]), acc[mi][ni], 0, 0, 0);
      }
    }
    __builtin_amdgcn_s_setprio(0);
  };

  i32x4 b0[8], b1[8];
  stageA(0, 0);
  asmB(b0, 0);
  stageA(1, 1);
  int bcur3 = 0, bstg3 = 2;

  for (int s = 0; s < NM64 - 2; s += 2) {
    asmB(b1, s + 1);
    asm volatile("s_waitcnt vmcnt(11)" ::: "memory");
    __builtin_amdgcn_s_barrier();
    __builtin_amdgcn_sched_barrier(0);
    stageA(bstg3, s + 2);
    compute(bcur3, b0);
    bcur3 = (bcur3 == 2) ? 0 : bcur3 + 1;
    bstg3 = (bstg3 == 2) ? 0 : bstg3 + 1;
    asmB(b0, s + 2);
    asm volatile("s_waitcnt vmcnt(11)" ::: "memory");
    __builtin_amdgcn_s_barrier();
    __builtin_amdgcn_sched_barrier(0);
    stageA(bstg3, s + 3);
    compute(bcur3, b1);
    bcur3 = (bcur3 == 2) ? 0 : bcur3 + 1;
    bstg3 = (bstg3 == 2) ? 0 : bstg3 + 1;
  }
  asmB(b1, NM64 - 1);
  asm volatile("s_waitcnt vmcnt(11)" ::: "memory");
  __builtin_amdgcn_s_barrier();
  __builtin_amdgcn_sched_barrier(0);
  compute(bcur3, b0);
  bcur3 = (bcur3 == 2) ? 0 : bcur3 + 1;
  asm volatile("s_waitcnt vmcnt(0)" ::: "memory");
  __builtin_amdgcn_s_barrier();
  __builtin_amdgcn_sched_barrier(0);
  compute(bcur3, b1);

  if (XSK) {
#pragma unroll
    for (int sx = 0; sx < 2; ++sx) {
      __syncthreads();
      stageX(sx, sx);
      if (sx) asmBx(b1, sx); else asmBx(b0, sx);
      asm volatile("s_waitcnt vmcnt(0)" ::: "memory");
      __syncthreads();
      __builtin_amdgcn_sched_barrier(0);
      compute(sx, sx ? (const i32x4*)b1 : (const i32x4*)b0);
    }
  }

  if (!XSK) {
    bf16_t* ob = outb + ((size_t)vt * S_TOT + s0) * 256;
#pragma unroll
    for (int ni = 0; ni < 4; ++ni) {
      int o = nw * 64 + ni * 16 + lo;
      float bv = bias[o];
      float s_ = 0.f, q_ = 0.f;
#pragma unroll
      for (int mi = 0; mi < 6; ++mi)
#pragma unroll
        for (int r2 = 0; r2 < 4; ++r2) {
          int srow = mi * 16 + hi * 4 + r2;
          float v = acc[mi][ni][r2] + bv;
          ob[(size_t)srow * 256 + o] = (bf16_t)v;
          s_ += v; q_ += v * v;
        }
      s_ += __shfl_xor(s_, 16); s_ += __shfl_xor(s_, 32);
      q_ += __shfl_xor(q_, 16); q_ += __shfl_xor(q_, 32);
      if (hi == 0) {
        atomicAdd(&sum_c[vt * 256 + o], s_);
        atomicAdd(&ss_c[vt * 256 + o], q_);
      }
    }
  } else {
    float* of = outf + ((size_t)vt * S_TOT + s0) * 256;
#pragma unroll
    for (int ni = 0; ni < 4; ++ni) {
      int o = nw * 64 + ni * 16 + lo;
      float bv = bias[o] + biask[o];
#pragma unroll
      for (int mi = 0; mi < 6; ++mi)
#pragma unroll
        for (int r2 = 0; r2 < 4; ++r2) {
          int srow = mi * 16 + hi * 4 + r2;
          of[(size_t)srow * 256 + o] = acc[mi][ni][r2] + bv;
        }
    }
  }
}

extern "C" void kernel_launch(void* const* d_in, const int* in_sizes, int n_in,
                              void* d_out, int out_size, void* d_ws, size_t ws_size,
                              hipStream_t stream) {
  const float* x      = (const float*)d_in[0];
  const int*   adjc   = (const int*)d_in[1];
  const float* gn1_s  = (const float*)d_in[2];
  const float* gn1_b  = (const float*)d_in[3];
  const float* gn2_s  = (const float*)d_in[4];
  const float* gn2_b  = (const float*)d_in[5];
  const float* W_skip = (const float*)d_in[6];
  const float* b_skip = (const float*)d_in[7];
  const float* W1     = (const float*)d_in[8];
  const float* b1     = (const float*)d_in[9];
  const float* W2     = (const float*)d_in[10];
  const float* b2     = (const float*)d_in[11];
  float* out = (float*)d_out;

  float* sum1  = (float*)d_ws;           // 128
  float* ss1   = sum1 + 128;             // 128
  float* sum_c = ss1 + 128;              // 1024
  float* ss_c  = sum_c + 1024;           // 1024
  float* pad   = ss_c + 1024;            // 3072 (layout pad)
  bf16_t* W1p  = (bf16_t*)(pad + 3072);  // 294912
  bf16_t* W2p  = W1p + 294912;           // 589824
  bf16_t* Wsp  = W2p + 589824;           // 32768
  bf16_t* h1   = Wsp + 32768;            // 6291456
  bf16_t* out1 = h1 + 6291456;           // 12582912 (reused in place as h2)

  hipMemsetAsync(sum1, 0, (128 + 128 + 1024 + 1024) * sizeof(float), stream);
  prep_kernel<<<640, 256, 0, stream>>>(W1, W2, W_skip, W1p, W2p, Wsp, x, sum1, ss1);
  apply_gn1<<<768, 256, 0, stream>>>(x, sum1, ss1, gn1_s, gn1_b, h1);
  conv_kernel<128, 18, false><<<512, 256, 0, stream>>>(
      h1, W1p, nullptr, nullptr, adjc, b1, nullptr, out1, nullptr, sum_c, ss_c);
  apply_gn2<<<1536, 256, 0, stream>>>(out1, sum_c, ss_c, gn2_s, gn2_b);
  conv_kernel<256, 36, true><<<512, 256, 0, stream>>>(
      out1, W2p, Wsp, x, adjc, b2, b_skip, nullptr, out, nullptr, nullptr);
}